// Round 4
// baseline (2889.884 us; speedup 1.0000x reference)
//
#include <hip/hip_runtime.h>
#include <cstdint>
#include <cstddef>

#define H_ 64
#define P_ 64
#define N_ 128
#define G_ 8
#define K_ 4
#define CS_ 256
#define EMB_ 2048
#define INTER_ 4096
#define CONV_DIM_ 6144
#define NGEMM1_ 10240   // gate + conv columns only (dt handled separately)
#define SEQ_ 4096
#define NC_ 16

typedef __attribute__((ext_vector_type(8))) short short8;
typedef __attribute__((ext_vector_type(8))) unsigned short ushort8_t;
typedef __attribute__((ext_vector_type(4))) float f32x4;

__device__ __forceinline__ float bf2f(unsigned short u) {
    return __uint_as_float(((unsigned int)u) << 16);
}
__device__ __forceinline__ unsigned short f2bf(float f) {
    unsigned int x = __float_as_uint(f);
    unsigned int r = (x + 0x7fffu + ((x >> 16) & 1u)) >> 16;  // RNE
    return (unsigned short)r;
}
__device__ __forceinline__ float sigmoidf_(float x) { return 1.f / (1.f + __expf(-x)); }

__device__ __forceinline__ float4 bfcvt_lo(ushort8_t v) {
    return make_float4(bf2f(v[0]), bf2f(v[1]), bf2f(v[2]), bf2f(v[3]));
}
__device__ __forceinline__ float4 bfcvt_hi(ushort8_t v) {
    return make_float4(bf2f(v[4]), bf2f(v[5]), bf2f(v[6]), bf2f(v[7]));
}

// ---------------- cast f32 -> bf16 (4 elems/thread) ----------------
__global__ void cast_f32_bf16(const float* __restrict__ in, unsigned short* __restrict__ out, int n4) {
    int i = blockIdx.x * 256 + threadIdx.x;
    if (i < n4) {
        float4 v = reinterpret_cast<const float4*>(in)[i];
        ushort4 o;
        o.x = f2bf(v.x); o.y = f2bf(v.y); o.z = f2bf(v.z); o.w = f2bf(v.w);
        reinterpret_cast<ushort4*>(out)[i] = o;
    }
}

// ---------------- bf16 MFMA GEMM: C[M][N] = A[M][K] * B[N][K]^T ----------------
// MODE 0: f32 output to Cf (stride N).
// MODE 1: split bf16 output: cols [0,INTER_) -> gateb, cols [INTER_, INTER_+CONV_DIM_) -> hbcb.
// Direct-from-global register tiling. Block = 256 thr = 4 waves (2x2), wave = 64x64.
template <int MODE>
__global__ void gemm_bt(const unsigned short* __restrict__ A, const unsigned short* __restrict__ B,
                        float* __restrict__ Cf, unsigned short* __restrict__ gateb,
                        unsigned short* __restrict__ hbcb, int M, int N, int K) {
    int tid = threadIdx.x;
    int lane = tid & 63;
    int wid = tid >> 6;
    int wm = wid >> 1, wn = wid & 1;
    int row0 = blockIdx.y * 128 + wm * 64;
    int col0 = blockIdx.x * 128 + wn * 64;
    int lr = lane & 15;   // A-row / B-col within fragment
    int lk = lane >> 4;   // k-group (0..3)

    f32x4 acc[4][4] = {};

    for (int k0 = 0; k0 < K; k0 += 32) {
        short8 a[4], b[4];
#pragma unroll
        for (int mi = 0; mi < 4; mi++) {
            int r = row0 + mi * 16 + lr;
            a[mi] = *reinterpret_cast<const short8*>(A + (size_t)r * K + k0 + lk * 8);
        }
#pragma unroll
        for (int ni = 0; ni < 4; ni++) {
            int c = col0 + ni * 16 + lr;
            b[ni] = *reinterpret_cast<const short8*>(B + (size_t)c * K + k0 + lk * 8);
        }
#pragma unroll
        for (int mi = 0; mi < 4; mi++)
#pragma unroll
            for (int ni = 0; ni < 4; ni++)
                acc[mi][ni] = __builtin_amdgcn_mfma_f32_16x16x32_bf16(a[mi], b[ni], acc[mi][ni], 0, 0, 0);
    }

    // C/D mapping: col = lane&15, row = (lane>>4)*4 + reg   [verified m89/m91]
#pragma unroll
    for (int mi = 0; mi < 4; mi++) {
        int rbase = row0 + mi * 16 + lk * 4;
#pragma unroll
        for (int ni = 0; ni < 4; ni++) {
            int c = col0 + ni * 16 + lr;
#pragma unroll
            for (int q = 0; q < 4; q++) {
                int rr = rbase + q;
                float v = acc[mi][ni][q];
                if (MODE == 0) {
                    Cf[(size_t)rr * N + c] = v;
                } else {
                    if (c < INTER_)
                        gateb[(size_t)rr * INTER_ + c] = f2bf(v);
                    else
                        hbcb[(size_t)rr * CONV_DIM_ + (c - INTER_)] = f2bf(v);
                }
            }
        }
    }
}

// ---------------- fp32 dt path: dt2[t][h] = softplus(X[t].W1row(10240+h) + dt_bias[h]) ----------------
__global__ void dt_kernel(const float* __restrict__ X, const float* __restrict__ W1,
                          const float* __restrict__ dt_bias, float* __restrict__ dt2) {
    int t = blockIdx.x;
    int tid = threadIdx.x;
    int h = tid >> 2, q = tid & 3;
    const float4* xr = reinterpret_cast<const float4*>(X + (size_t)t * EMB_);
    const float4* wr = reinterpret_cast<const float4*>(W1 + (size_t)(INTER_ + CONV_DIM_ + h) * EMB_);
    int base = q * 128;
    float s0 = 0.f, s1 = 0.f, s2 = 0.f, s3 = 0.f;
#pragma unroll 8
    for (int k4 = 0; k4 < 128; k4++) {
        float4 a = xr[base + k4], b = wr[base + k4];
        s0 = fmaf(a.x, b.x, s0);
        s1 = fmaf(a.y, b.y, s1);
        s2 = fmaf(a.z, b.z, s2);
        s3 = fmaf(a.w, b.w, s3);
    }
    float s = (s0 + s1) + (s2 + s3);
    s += __shfl_xor(s, 1);
    s += __shfl_xor(s, 2);
    if (q == 0) {
        float v = s + dt_bias[h];
        float sp = (v > 20.f) ? v : log1pf(__expf(v));
        dt2[(size_t)t * H_ + h] = sp;
    }
}

// ---------------- depthwise causal conv (K=4) + SiLU, bf16 in/out ----------------
__global__ void conv_kernel(const unsigned short* __restrict__ hbcb, const float* __restrict__ cw,
                            const float* __restrict__ cb, unsigned short* __restrict__ convb) {
    int c = blockIdx.x * 256 + threadIdx.x;  // 0..6143
    int t = blockIdx.y;
    float acc = cb[c];
#pragma unroll
    for (int k = 0; k < K_; k++) {
        int tt = t - (K_ - 1) + k;
        if (tt >= 0)
            acc = fmaf(bf2f(hbcb[(size_t)tt * CONV_DIM_ + c]), cw[c * K_ + k], acc);
    }
    float s = acc * sigmoidf_(acc);
    convb[(size_t)t * CONV_DIM_ + c] = f2bf(s);
}

// ---------------- SSD: one block per (chunk, head), bf16 conv input ----------------
__launch_bounds__(256)
__global__ void ssd_kernel(const unsigned short* __restrict__ convb, const float* __restrict__ dt2,
                           const float* __restrict__ A_log, const float* __restrict__ Dv,
                           float* __restrict__ ybuf) {
    __shared__ float4 Bs4[64 * 32];   // 64 rows x 128 cols f32
    __shared__ float4 hs4[64 * 16];   // 64 rows x 64 cols f32 (hidden * dt2)
    __shared__ float acum[CS_];

    int h = blockIdx.x & 63;
    int c = blockIdx.x >> 6;
    int g = h & 7;  // jnp.tile -> head h uses group h % G
    int i = threadIdx.x;
    size_t rowbase = (size_t)c * CS_;

    float Aneg = -__expf(A_log[h]);
    float my_dt = dt2[(rowbase + i) * H_ + h];
    acum[i] = Aneg * my_dt;
    __syncthreads();
    // inclusive scan (Hillis-Steele)
    for (int off = 1; off < CS_; off <<= 1) {
        float v = (i >= off) ? acum[i - off] : 0.f;
        __syncthreads();
        acum[i] += v;
        __syncthreads();
    }
    float myac = acum[i];
    float lasta = acum[CS_ - 1];

    // C row of this thread: 128 f32 in regs (converted from bf16)
    float4 Cr[32];
    {
        const ushort8_t* crow = reinterpret_cast<const ushort8_t*>(
            convb + (rowbase + i) * CONV_DIM_ + INTER_ + G_ * N_ + (size_t)g * N_);
#pragma unroll
        for (int k8 = 0; k8 < 16; k8++) {
            ushort8_t v = crow[k8];
            Cr[k8 * 2 + 0] = bfcvt_lo(v);
            Cr[k8 * 2 + 1] = bfcvt_hi(v);
        }
    }

    float4 Y[16];
#pragma unroll
    for (int p = 0; p < 16; p++) Y[p] = make_float4(0.f, 0.f, 0.f, 0.f);

    for (int jt = 0; jt < 4; jt++) {
        __syncthreads();
        int jbase = jt * 64;
        // stage B tile: 64 rows x 128 bf16 = 1024 ushort8 chunks
#pragma unroll
        for (int u = 0; u < 4; u++) {
            int q = u * 256 + i;
            int jj = q >> 4, c8 = q & 15;
            ushort8_t v = *reinterpret_cast<const ushort8_t*>(
                convb + (rowbase + jbase + jj) * CONV_DIM_ + INTER_ + (size_t)g * N_ + c8 * 8);
            Bs4[jj * 32 + c8 * 2 + 0] = bfcvt_lo(v);
            Bs4[jj * 32 + c8 * 2 + 1] = bfcvt_hi(v);
        }
        // stage hid*dt2 tile: 64 rows x 64 bf16 = 512 ushort8 chunks
#pragma unroll
        for (int u = 0; u < 2; u++) {
            int q = u * 256 + i;
            int jj = q >> 3, p8 = q & 7;
            float dts = dt2[(rowbase + jbase + jj) * H_ + h];
            ushort8_t v = *reinterpret_cast<const ushort8_t*>(
                convb + (rowbase + jbase + jj) * CONV_DIM_ + (size_t)h * P_ + p8 * 8);
            float4 lo = bfcvt_lo(v), hi = bfcvt_hi(v);
            lo.x *= dts; lo.y *= dts; lo.z *= dts; lo.w *= dts;
            hi.x *= dts; hi.y *= dts; hi.z *= dts; hi.w *= dts;
            hs4[jj * 16 + p8 * 2 + 0] = lo;
            hs4[jj * 16 + p8 * 2 + 1] = hi;
        }
        __syncthreads();

        for (int jj = 0; jj < 64; jj++) {
            float s0 = 0.f, s1 = 0.f, s2 = 0.f, s3 = 0.f;
#pragma unroll
            for (int k4 = 0; k4 < 32; k4++) {
                float4 b = Bs4[jj * 32 + k4];
                s0 = fmaf(Cr[k4].x, b.x, s0);
                s1 = fmaf(Cr[k4].y, b.y, s1);
                s2 = fmaf(Cr[k4].z, b.z, s2);
                s3 = fmaf(Cr[k4].w, b.w, s3);
            }
            float s = (s0 + s1) + (s2 + s3);
            int j = jbase + jj;
            float aj = acum[j];
            // off-diagonal (state) term: always; intra-chunk term: j<=i
            float wsum = __expf(myac + lasta - aj);
            if (j <= i) wsum += __expf(myac - aj);
            float w = s * wsum;
#pragma unroll
            for (int p = 0; p < 16; p++) {
                float4 hv = hs4[jj * 16 + p];
                Y[p].x = fmaf(w, hv.x, Y[p].x);
                Y[p].y = fmaf(w, hv.y, Y[p].y);
                Y[p].z = fmaf(w, hv.z, Y[p].z);
                Y[p].w = fmaf(w, hv.w, Y[p].w);
            }
        }
    }

    // D residual + write
    float Dh = Dv[h];
    const ushort8_t* hidr = reinterpret_cast<const ushort8_t*>(
        convb + (rowbase + i) * CONV_DIM_ + (size_t)h * P_);
    float4* yout = reinterpret_cast<float4*>(ybuf + (rowbase + i) * INTER_ + (size_t)h * P_);
#pragma unroll
    for (int p8 = 0; p8 < 8; p8++) {
        ushort8_t v = hidr[p8];
        float4 lo = bfcvt_lo(v), hi = bfcvt_hi(v);
        float4 o0 = Y[p8 * 2 + 0], o1 = Y[p8 * 2 + 1];
        o0.x = fmaf(Dh, lo.x, o0.x); o0.y = fmaf(Dh, lo.y, o0.y);
        o0.z = fmaf(Dh, lo.z, o0.z); o0.w = fmaf(Dh, lo.w, o0.w);
        o1.x = fmaf(Dh, hi.x, o1.x); o1.y = fmaf(Dh, hi.y, o1.y);
        o1.z = fmaf(Dh, hi.z, o1.z); o1.w = fmaf(Dh, hi.w, o1.w);
        yout[p8 * 2 + 0] = o0;
        yout[p8 * 2 + 1] = o1;
    }
}

// ---------------- gate-SiLU + RMSNorm -> bf16 ----------------
__global__ void gatenorm_kernel(const float* __restrict__ ybuf, const unsigned short* __restrict__ gateb,
                                const float* __restrict__ norm_w, unsigned short* __restrict__ nb) {
    int t = blockIdx.x;
    int tid = threadIdx.x;
    __shared__ float red[4];
    float yg[16];
    float ss = 0.f;
#pragma unroll
    for (int u = 0; u < 4; u++) {
        int f4 = u * 256 + tid;
        float4 yv = reinterpret_cast<const float4*>(ybuf + (size_t)t * INTER_)[f4];
        ushort4 gu = reinterpret_cast<const ushort4*>(gateb + (size_t)t * INTER_)[f4];
        float g0 = bf2f(gu.x), g1 = bf2f(gu.y), g2 = bf2f(gu.z), g3 = bf2f(gu.w);
        float v0 = yv.x * g0 * sigmoidf_(g0);
        float v1 = yv.y * g1 * sigmoidf_(g1);
        float v2 = yv.z * g2 * sigmoidf_(g2);
        float v3 = yv.w * g3 * sigmoidf_(g3);
        yg[u * 4 + 0] = v0; yg[u * 4 + 1] = v1; yg[u * 4 + 2] = v2; yg[u * 4 + 3] = v3;
        ss += v0 * v0 + v1 * v1 + v2 * v2 + v3 * v3;
    }
#pragma unroll
    for (int off = 32; off > 0; off >>= 1) ss += __shfl_xor(ss, off);
    if ((tid & 63) == 0) red[tid >> 6] = ss;
    __syncthreads();
    float tot = red[0] + red[1] + red[2] + red[3];
    float scale = rsqrtf(tot / (float)INTER_ + 1e-6f);
#pragma unroll
    for (int u = 0; u < 4; u++) {
        int f4 = u * 256 + tid;
        float4 nw = reinterpret_cast<const float4*>(norm_w)[f4];
        ushort4 o;
        o.x = f2bf(nw.x * yg[u * 4 + 0] * scale);
        o.y = f2bf(nw.y * yg[u * 4 + 1] * scale);
        o.z = f2bf(nw.z * yg[u * 4 + 2] * scale);
        o.w = f2bf(nw.w * yg[u * 4 + 3] * scale);
        reinterpret_cast<ushort4*>(nb + (size_t)t * INTER_)[f4] = o;
    }
}

extern "C" void kernel_launch(void* const* d_in, const int* in_sizes, int n_in,
                              void* d_out, int out_size, void* d_ws, size_t ws_size,
                              hipStream_t stream) {
    const float* X    = (const float*)d_in[0];
    const float* W1   = (const float*)d_in[1];
    const float* CW   = (const float*)d_in[2];
    const float* CB   = (const float*)d_in[3];
    const float* DTB  = (const float*)d_in[4];
    const float* ALOG = (const float*)d_in[5];
    const float* DD   = (const float*)d_in[6];
    const float* NW   = (const float*)d_in[7];
    const float* W2   = (const float*)d_in[8];
    float* out = (float*)d_out;

    // ---- workspace layout with lifetime aliasing (total 177,471,488 B) ----
    // [0, 58.98M):   W1b(42.2M)+Xb(16.8M) [casts->gemm1] -> convb(50.3M) [conv->ssd] -> nb(33.6M) [gatenorm->gemm2]
    // [58.98M, 92.5M):  gateb 33.6M  [gemm1 -> gatenorm]
    // [92.5M, 159.6M):  hbcb 50.3M [gemm1 -> conv] -> ybuf 67.1M [ssd -> gatenorm]
    // [159.6M, 160.7M): dt2 1.05M [dt -> ssd]
    // [160.7M, 177.5M): W2b 16.8M [cast -> gemm2]
    char* ws = (char*)d_ws;
    unsigned short* W1b   = (unsigned short*)(ws + 0);
    unsigned short* Xb    = (unsigned short*)(ws + 42205184);
    unsigned short* convb = (unsigned short*)(ws + 0);
    unsigned short* nb    = (unsigned short*)(ws + 0);
    unsigned short* gateb = (unsigned short*)(ws + 58982400);
    unsigned short* hbcb  = (unsigned short*)(ws + 92536832);
    float*          ybuf  = (float*)         (ws + 92536832);
    float*          dt2   = (float*)         (ws + 159645696);
    unsigned short* W2b   = (unsigned short*)(ws + 160694272);

    cast_f32_bf16<<<(SEQ_ * EMB_ / 4) / 256, 256, 0, stream>>>(X, Xb, SEQ_ * EMB_ / 4);
    cast_f32_bf16<<<(10304 * EMB_ / 4 + 255) / 256, 256, 0, stream>>>(W1, W1b, 10304 * EMB_ / 4);
    cast_f32_bf16<<<(EMB_ * INTER_ / 4) / 256, 256, 0, stream>>>(W2, W2b, EMB_ * INTER_ / 4);

    dim3 g1(NGEMM1_ / 128, SEQ_ / 128);
    gemm_bt<1><<<g1, 256, 0, stream>>>(Xb, W1b, nullptr, gateb, hbcb, SEQ_, NGEMM1_, EMB_);

    dt_kernel<<<SEQ_, 256, 0, stream>>>(X, W1, DTB, dt2);

    conv_kernel<<<dim3(CONV_DIM_ / 256, SEQ_), 256, 0, stream>>>(hbcb, CW, CB, convb);

    ssd_kernel<<<NC_ * H_, 256, 0, stream>>>(convb, dt2, ALOG, DD, ybuf);

    gatenorm_kernel<<<SEQ_, 256, 0, stream>>>(ybuf, gateb, NW, nb);

    dim3 g2(EMB_ / 128, SEQ_ / 128);
    gemm_bt<0><<<g2, 256, 0, stream>>>(nb, W2b, out, nullptr, nullptr, SEQ_, EMB_, INTER_);
}

// Round 10
// 1953.077 us; speedup vs baseline: 1.4797x; 1.4797x over previous
//
#include <hip/hip_runtime.h>
#include <cstdint>
#include <cstddef>

#define H_ 64
#define P_ 64
#define N_ 128
#define G_ 8
#define K_ 4
#define CS_ 256
#define EMB_ 2048
#define INTER_ 4096
#define CONV_DIM_ 6144
#define NGEMM1_ 10240   // gate + conv columns only (dt handled separately)
#define SEQ_ 4096
#define NC_ 16
#define LOG2E_ 1.44269504f

typedef __attribute__((ext_vector_type(8))) short short8;
typedef __attribute__((ext_vector_type(8))) unsigned short ushort8_t;
typedef __attribute__((ext_vector_type(4))) float f32x4;

__device__ __forceinline__ float bf2f(unsigned short u) {
    return __uint_as_float(((unsigned int)u) << 16);
}
__device__ __forceinline__ unsigned short f2bf(float f) {
    unsigned int x = __float_as_uint(f);
    unsigned int r = (x + 0x7fffu + ((x >> 16) & 1u)) >> 16;  // RNE
    return (unsigned short)r;
}
__device__ __forceinline__ float sigmoidf_(float x) { return 1.f / (1.f + __expf(-x)); }

__device__ __forceinline__ float4 bfcvt_lo(ushort8_t v) {
    return make_float4(bf2f(v[0]), bf2f(v[1]), bf2f(v[2]), bf2f(v[3]));
}
__device__ __forceinline__ float4 bfcvt_hi(ushort8_t v) {
    return make_float4(bf2f(v[4]), bf2f(v[5]), bf2f(v[6]), bf2f(v[7]));
}

// ---------------- cast f32 -> bf16 (4 elems/thread) ----------------
__global__ void cast_f32_bf16(const float* __restrict__ in, unsigned short* __restrict__ out, int n4) {
    int i = blockIdx.x * 256 + threadIdx.x;
    if (i < n4) {
        float4 v = reinterpret_cast<const float4*>(in)[i];
        ushort4 o;
        o.x = f2bf(v.x); o.y = f2bf(v.y); o.z = f2bf(v.z); o.w = f2bf(v.w);
        reinterpret_cast<ushort4*>(out)[i] = o;
    }
}

// ---------------- bf16 MFMA GEMM: C[M][N] = A[M][K] * B[N][K]^T ----------------
template <int MODE>
__global__ void gemm_bt(const unsigned short* __restrict__ A, const unsigned short* __restrict__ B,
                        float* __restrict__ Cf, unsigned short* __restrict__ gateb,
                        unsigned short* __restrict__ hbcb, int M, int N, int K) {
    int tid = threadIdx.x;
    int lane = tid & 63;
    int wid = tid >> 6;
    int wm = wid >> 1, wn = wid & 1;
    int row0 = blockIdx.y * 128 + wm * 64;
    int col0 = blockIdx.x * 128 + wn * 64;
    int lr = lane & 15;   // A-row / B-col within fragment
    int lk = lane >> 4;   // k-group (0..3)

    f32x4 acc[4][4] = {};

    for (int k0 = 0; k0 < K; k0 += 32) {
        short8 a[4], b[4];
#pragma unroll
        for (int mi = 0; mi < 4; mi++) {
            int r = row0 + mi * 16 + lr;
            a[mi] = *reinterpret_cast<const short8*>(A + (size_t)r * K + k0 + lk * 8);
        }
#pragma unroll
        for (int ni = 0; ni < 4; ni++) {
            int c = col0 + ni * 16 + lr;
            b[ni] = *reinterpret_cast<const short8*>(B + (size_t)c * K + k0 + lk * 8);
        }
#pragma unroll
        for (int mi = 0; mi < 4; mi++)
#pragma unroll
            for (int ni = 0; ni < 4; ni++)
                acc[mi][ni] = __builtin_amdgcn_mfma_f32_16x16x32_bf16(a[mi], b[ni], acc[mi][ni], 0, 0, 0);
    }

    // C/D mapping: col = lane&15, row = (lane>>4)*4 + reg
#pragma unroll
    for (int mi = 0; mi < 4; mi++) {
        int rbase = row0 + mi * 16 + lk * 4;
#pragma unroll
        for (int ni = 0; ni < 4; ni++) {
            int c = col0 + ni * 16 + lr;
#pragma unroll
            for (int q = 0; q < 4; q++) {
                int rr = rbase + q;
                float v = acc[mi][ni][q];
                if (MODE == 0) {
                    Cf[(size_t)rr * N + c] = v;
                } else {
                    if (c < INTER_)
                        gateb[(size_t)rr * INTER_ + c] = f2bf(v);
                    else
                        hbcb[(size_t)rr * CONV_DIM_ + (c - INTER_)] = f2bf(v);
                }
            }
        }
    }
}

// ---------------- fp32 dt path ----------------
__global__ void dt_kernel(const float* __restrict__ X, const float* __restrict__ W1,
                          const float* __restrict__ dt_bias, float* __restrict__ dt2) {
    int t = blockIdx.x;
    int tid = threadIdx.x;
    int h = tid >> 2, q = tid & 3;
    const float4* xr = reinterpret_cast<const float4*>(X + (size_t)t * EMB_);
    const float4* wr = reinterpret_cast<const float4*>(W1 + (size_t)(INTER_ + CONV_DIM_ + h) * EMB_);
    int base = q * 128;
    float s0 = 0.f, s1 = 0.f, s2 = 0.f, s3 = 0.f;
#pragma unroll 8
    for (int k4 = 0; k4 < 128; k4++) {
        float4 a = xr[base + k4], b = wr[base + k4];
        s0 = fmaf(a.x, b.x, s0);
        s1 = fmaf(a.y, b.y, s1);
        s2 = fmaf(a.z, b.z, s2);
        s3 = fmaf(a.w, b.w, s3);
    }
    float s = (s0 + s1) + (s2 + s3);
    s += __shfl_xor(s, 1);
    s += __shfl_xor(s, 2);
    if (q == 0) {
        float v = s + dt_bias[h];
        float sp = (v > 20.f) ? v : log1pf(__expf(v));
        dt2[(size_t)t * H_ + h] = sp;
    }
}

// ---------------- depthwise causal conv (K=4) + SiLU, bf16 in/out ----------------
__global__ void conv_kernel(const unsigned short* __restrict__ hbcb, const float* __restrict__ cw,
                            const float* __restrict__ cb, unsigned short* __restrict__ convb) {
    int c = blockIdx.x * 256 + threadIdx.x;  // 0..6143
    int t = blockIdx.y;
    float acc = cb[c];
#pragma unroll
    for (int k = 0; k < K_; k++) {
        int tt = t - (K_ - 1) + k;
        if (tt >= 0)
            acc = fmaf(bf2f(hbcb[(size_t)tt * CONV_DIM_ + c]), cw[c * K_ + k], acc);
    }
    float s = acc * sigmoidf_(acc);
    convb[(size_t)t * CONV_DIM_ + c] = f2bf(s);
}

// ---------------- SSD via MFMA: one block per (chunk, head) ----------------
// 4 waves; wave w owns chunk rows [w*64, w*64+64). Per j-tile (64 j):
//   S = C.B^T (mfma), weight in-register (exp2), P->bf16->LDS (swizzled),
//   Y += P.hdT (mfma). D-residual at epilogue from L2-hot global.
__launch_bounds__(256, 2)
__global__ void ssd_mfma(const unsigned short* __restrict__ convb, const float* __restrict__ dt2,
                         const float* __restrict__ A_log, const float* __restrict__ Dv,
                         float* __restrict__ ybuf) {
    __shared__ float acum[CS_];                 // log2-scaled cumsum of a = A*dt
    __shared__ unsigned short Bs[64 * 128];     // B j-tile, row stride 128 us (256B), XOR-swizzled
    __shared__ unsigned short hdT[64 * 64];     // (hid*dt)^T [p][j], row stride 64 us (128B), swizzled
    __shared__ unsigned short Ps[4][64 * 64];   // per-wave P tile [i][j], swizzled

    int h = blockIdx.x & 63;
    int c = blockIdx.x >> 6;
    int g = h & 7;
    int tid = threadIdx.x;
    int lane = tid & 63;
    int w = tid >> 6;
    int lr = lane & 15, lk = lane >> 4;
    size_t rowbase = (size_t)c * CS_;
    const unsigned short* convB = convb + INTER_ + (size_t)g * N_;          // B cols
    const unsigned short* convC = convb + INTER_ + G_ * N_ + (size_t)g * N_; // C cols
    const unsigned short* convH = convb + (size_t)h * P_;                    // hidden cols

    // ---- scan of a = A*dt (log2 units) ----
    float Aneg = -__expf(A_log[h]);
    float mydt = dt2[(rowbase + tid) * H_ + h];
    acum[tid] = Aneg * mydt * LOG2E_;
    __syncthreads();
    for (int off = 1; off < CS_; off <<= 1) {
        float v = (tid >= off) ? acum[tid - off] : 0.f;
        __syncthreads();
        acum[tid] += v;
        __syncthreads();
    }
    float last2 = acum[CS_ - 1];

    int ibase = w * 64;
    float ac_i[4][4];
#pragma unroll
    for (int mi = 0; mi < 4; mi++)
#pragma unroll
        for (int q = 0; q < 4; q++)
            ac_i[mi][q] = acum[ibase + mi * 16 + lk * 4 + q];

    // ---- C fragments for this wave's 64 rows, K=128 (16 x short8 in regs) ----
    short8 cf[4][4];
#pragma unroll
    for (int mi = 0; mi < 4; mi++) {
        size_t r = rowbase + ibase + mi * 16 + lr;
#pragma unroll
        for (int kt = 0; kt < 4; kt++)
            cf[mi][kt] = *reinterpret_cast<const short8*>(convC + r * CONV_DIM_ + kt * 32 + lk * 8);
    }

    f32x4 accy[4][4] = {};

    for (int jt = 0; jt < 4; jt++) {
        __syncthreads();
        // ---- stage B j-tile: 64 rows x 128 bf16, swizzle slot ^= (j&15) ----
#pragma unroll
        for (int u = 0; u < 4; u++) {
            int chunk = u * 256 + tid;
            int j = chunk >> 4, c16 = chunk & 15;
            short8 v = *reinterpret_cast<const short8*>(convB + (rowbase + jt * 64 + j) * CONV_DIM_ + c16 * 8);
            *reinterpret_cast<short8*>(Bs + j * 128 + ((c16 * 8) ^ ((j & 15) << 3))) = v;
        }
        // ---- stage (hid*dt)^T: [p][j], scattered b16 writes, swizzle ^= (p&7) ----
#pragma unroll
        for (int u = 0; u < 2; u++) {
            int chunk = u * 256 + tid;
            int j = chunk >> 3, p8 = chunk & 7;
            float dts = dt2[(rowbase + jt * 64 + j) * H_ + h];
            ushort8_t v = *reinterpret_cast<const ushort8_t*>(convH + (rowbase + jt * 64 + j) * CONV_DIM_ + p8 * 8);
#pragma unroll
            for (int e = 0; e < 8; e++) {
                int p = p8 * 8 + e;
                int col = j;
                int swz = (p & 7) << 3;                      // ushort-unit XOR on bits 3..5
                hdT[p * 64 + (((col & ~7) ) ^ swz) + (col & 7)] = f2bf(bf2f(v[e]) * dts);
            }
        }
        __syncthreads();

        // ---- S = C . B^T over this j-tile ----
        f32x4 acc[4][4] = {};
#pragma unroll
        for (int kt = 0; kt < 4; kt++) {
            short8 bf[4];
#pragma unroll
            for (int ni = 0; ni < 4; ni++) {
                int jb = ni * 16 + lr;
                bf[ni] = *reinterpret_cast<const short8*>(Bs + jb * 128 + ((kt * 32 + lk * 8) ^ ((jb & 15) << 3)));
            }
#pragma unroll
            for (int mi = 0; mi < 4; mi++)
#pragma unroll
                for (int ni = 0; ni < 4; ni++)
                    acc[mi][ni] = __builtin_amdgcn_mfma_f32_16x16x32_bf16(cf[mi][kt], bf[ni], acc[mi][ni], 0, 0, 0);
        }

        // ---- weight + convert to bf16 P, write to per-wave swizzled LDS ----
#pragma unroll
        for (int ni = 0; ni < 4; ni++) {
            int jl = ni * 16 + lr;
            float a_j = acum[jt * 64 + jl];
            int jg = jt * 64 + jl;
#pragma unroll
            for (int mi = 0; mi < 4; mi++) {
#pragma unroll
                for (int q = 0; q < 4; q++) {
                    int il = mi * 16 + lk * 4 + q;
                    int ig = ibase + il;
                    float arg = ac_i[mi][q] - a_j;
                    float e = exp2f(arg + last2);
                    if (jg <= ig) e += exp2f(arg);
                    float pv = acc[mi][ni][q] * e;
                    int swz = (il & 7) << 3;
                    Ps[w][il * 64 + (((jl & ~7)) ^ swz) + (jl & 7)] = f2bf(pv);
                }
            }
        }
        __syncthreads();

        // ---- Y += P . hdT ----
#pragma unroll
        for (int jm = 0; jm < 2; jm++) {
            short8 pa[4], hb[4];
#pragma unroll
            for (int mi = 0; mi < 4; mi++) {
                int il = mi * 16 + lr;
                pa[mi] = *reinterpret_cast<const short8*>(Ps[w] + il * 64 + ((jm * 32 + lk * 8) ^ ((il & 7) << 3)));
            }
#pragma unroll
            for (int np = 0; np < 4; np++) {
                int p = np * 16 + lr;
                hb[np] = *reinterpret_cast<const short8*>(hdT + p * 64 + ((jm * 32 + lk * 8) ^ ((p & 7) << 3)));
            }
#pragma unroll
            for (int mi = 0; mi < 4; mi++)
#pragma unroll
                for (int np = 0; np < 4; np++)
                    accy[mi][np] = __builtin_amdgcn_mfma_f32_16x16x32_bf16(pa[mi], hb[np], accy[mi][np], 0, 0, 0);
        }
    }

    // ---- epilogue: Y + D*hid -> ybuf (f32) ----
    float Dh = Dv[h];
#pragma unroll
    for (int mi = 0; mi < 4; mi++) {
#pragma unroll
        for (int q = 0; q < 4; q++) {
            size_t t = rowbase + ibase + mi * 16 + lk * 4 + q;
            const unsigned short* hrow = convH + t * CONV_DIM_;
            float* yrow = ybuf + t * INTER_ + (size_t)h * P_;
#pragma unroll
            for (int np = 0; np < 4; np++) {
                int p = np * 16 + lr;
                yrow[p] = accy[mi][np][q] + Dh * bf2f(hrow[p]);
            }
        }
    }
}

// ---------------- gate-SiLU + RMSNorm -> bf16 ----------------
__global__ void gatenorm_kernel(const float* __restrict__ ybuf, const unsigned short* __restrict__ gateb,
                                const float* __restrict__ norm_w, unsigned short* __restrict__ nb) {
    int t = blockIdx.x;
    int tid = threadIdx.x;
    __shared__ float red[4];
    float yg[16];
    float ss = 0.f;
#pragma unroll
    for (int u = 0; u < 4; u++) {
        int f4 = u * 256 + tid;
        float4 yv = reinterpret_cast<const float4*>(ybuf + (size_t)t * INTER_)[f4];
        ushort4 gu = reinterpret_cast<const ushort4*>(gateb + (size_t)t * INTER_)[f4];
        float g0 = bf2f(gu.x), g1 = bf2f(gu.y), g2 = bf2f(gu.z), g3 = bf2f(gu.w);
        float v0 = yv.x * g0 * sigmoidf_(g0);
        float v1 = yv.y * g1 * sigmoidf_(g1);
        float v2 = yv.z * g2 * sigmoidf_(g2);
        float v3 = yv.w * g3 * sigmoidf_(g3);
        yg[u * 4 + 0] = v0; yg[u * 4 + 1] = v1; yg[u * 4 + 2] = v2; yg[u * 4 + 3] = v3;
        ss += v0 * v0 + v1 * v1 + v2 * v2 + v3 * v3;
    }
#pragma unroll
    for (int off = 32; off > 0; off >>= 1) ss += __shfl_xor(ss, off);
    if ((tid & 63) == 0) red[tid >> 6] = ss;
    __syncthreads();
    float tot = red[0] + red[1] + red[2] + red[3];
    float scale = rsqrtf(tot / (float)INTER_ + 1e-6f);
#pragma unroll
    for (int u = 0; u < 4; u++) {
        int f4 = u * 256 + tid;
        float4 nw = reinterpret_cast<const float4*>(norm_w)[f4];
        ushort4 o;
        o.x = f2bf(nw.x * yg[u * 4 + 0] * scale);
        o.y = f2bf(nw.y * yg[u * 4 + 1] * scale);
        o.z = f2bf(nw.z * yg[u * 4 + 2] * scale);
        o.w = f2bf(nw.w * yg[u * 4 + 3] * scale);
        reinterpret_cast<ushort4*>(nb + (size_t)t * INTER_)[f4] = o;
    }
}

extern "C" void kernel_launch(void* const* d_in, const int* in_sizes, int n_in,
                              void* d_out, int out_size, void* d_ws, size_t ws_size,
                              hipStream_t stream) {
    const float* X    = (const float*)d_in[0];
    const float* W1   = (const float*)d_in[1];
    const float* CW   = (const float*)d_in[2];
    const float* CB   = (const float*)d_in[3];
    const float* DTB  = (const float*)d_in[4];
    const float* ALOG = (const float*)d_in[5];
    const float* DD   = (const float*)d_in[6];
    const float* NW   = (const float*)d_in[7];
    const float* W2   = (const float*)d_in[8];
    float* out = (float*)d_out;

    // ---- workspace layout with lifetime aliasing (total 177,471,488 B) ----
    char* ws = (char*)d_ws;
    unsigned short* W1b   = (unsigned short*)(ws + 0);
    unsigned short* Xb    = (unsigned short*)(ws + 42205184);
    unsigned short* convb = (unsigned short*)(ws + 0);
    unsigned short* nb    = (unsigned short*)(ws + 0);
    unsigned short* gateb = (unsigned short*)(ws + 58982400);
    unsigned short* hbcb  = (unsigned short*)(ws + 92536832);
    float*          ybuf  = (float*)         (ws + 92536832);
    float*          dt2   = (float*)         (ws + 159645696);
    unsigned short* W2b   = (unsigned short*)(ws + 160694272);

    cast_f32_bf16<<<(SEQ_ * EMB_ / 4) / 256, 256, 0, stream>>>(X, Xb, SEQ_ * EMB_ / 4);
    cast_f32_bf16<<<(10304 * EMB_ / 4 + 255) / 256, 256, 0, stream>>>(W1, W1b, 10304 * EMB_ / 4);
    cast_f32_bf16<<<(EMB_ * INTER_ / 4) / 256, 256, 0, stream>>>(W2, W2b, EMB_ * INTER_ / 4);

    dim3 g1(NGEMM1_ / 128, SEQ_ / 128);
    gemm_bt<1><<<g1, 256, 0, stream>>>(Xb, W1b, nullptr, gateb, hbcb, SEQ_, NGEMM1_, EMB_);

    dt_kernel<<<SEQ_, 256, 0, stream>>>(X, W1, DTB, dt2);

    conv_kernel<<<dim3(CONV_DIM_ / 256, SEQ_), 256, 0, stream>>>(hbcb, CW, CB, convb);

    ssd_mfma<<<NC_ * H_, 256, 0, stream>>>(convb, dt2, ALOG, DD, ybuf);

    gatenorm_kernel<<<SEQ_, 256, 0, stream>>>(ybuf, gateb, NW, nb);

    dim3 g2(EMB_ / 128, SEQ_ / 128);
    gemm_bt<0><<<g2, 256, 0, stream>>>(nb, W2b, out, nullptr, nullptr, SEQ_, EMB_, INTER_);
}

// Round 14
// 1388.461 us; speedup vs baseline: 2.0814x; 1.4066x over previous
//
#include <hip/hip_runtime.h>
#include <cstdint>
#include <cstddef>

#define H_ 64
#define P_ 64
#define N_ 128
#define G_ 8
#define K_ 4
#define CS_ 256
#define EMB_ 2048
#define INTER_ 4096
#define CONV_DIM_ 6144
#define NGEMM1_ 10240   // gate + conv columns only (dt handled separately)
#define SEQ_ 4096
#define NC_ 16
#define LOG2E_ 1.44269504f

typedef __attribute__((ext_vector_type(8))) short short8;
typedef __attribute__((ext_vector_type(8))) unsigned short ushort8_t;
typedef __attribute__((ext_vector_type(4))) float f32x4;

__device__ __forceinline__ float bf2f(unsigned short u) {
    return __uint_as_float(((unsigned int)u) << 16);
}
__device__ __forceinline__ unsigned short f2bf(float f) {
    unsigned int x = __float_as_uint(f);
    unsigned int r = (x + 0x7fffu + ((x >> 16) & 1u)) >> 16;  // RNE
    return (unsigned short)r;
}
__device__ __forceinline__ float sigmoidf_(float x) { return 1.f / (1.f + __expf(-x)); }

// ---------------- cast f32 -> bf16 (4 elems/thread) ----------------
__global__ void cast_f32_bf16(const float* __restrict__ in, unsigned short* __restrict__ out, int n4) {
    int i = blockIdx.x * 256 + threadIdx.x;
    if (i < n4) {
        float4 v = reinterpret_cast<const float4*>(in)[i];
        ushort4 o;
        o.x = f2bf(v.x); o.y = f2bf(v.y); o.z = f2bf(v.z); o.w = f2bf(v.w);
        reinterpret_cast<ushort4*>(out)[i] = o;
    }
}

// ---- one 1KB global->LDS staging instruction: 16 rows x 32 bf16 (64B/row) ----
// LDS dest is wave-uniform base + lane*16 (HW); layout matches linear row-major
// [16][32] bf16 because chunk*1024 + lane*16 == row*64 + slot*16 with
// row = lane>>2, slot = lane&3.
__device__ __forceinline__ void stage_1k(const unsigned short* __restrict__ gsrc, size_t gstride_elems,
                                         unsigned short* lds, int lane) {
    const unsigned short* ga = gsrc + (size_t)(lane >> 2) * gstride_elems + (lane & 3) * 8;
    __builtin_amdgcn_global_load_lds(
        (const __attribute__((address_space(1))) unsigned int*)ga,
        (__attribute__((address_space(3))) unsigned int*)lds,
        16, 0, 0);
}

// ---------------- LDS-staged bf16 MFMA GEMM (m97 pattern): C = A[M,K] . B[N,K]^T ----------------
// 128x128 tile, BK=32, 4 waves (2x2 of 64x64), double-buffered LDS, global_load_lds w=16.
template <int MODE>
__launch_bounds__(256)
__global__ void gemm_lds(const unsigned short* __restrict__ A, const unsigned short* __restrict__ B,
                         float* __restrict__ Cf, unsigned short* __restrict__ gateb,
                         unsigned short* __restrict__ hbcb, int M, int N, int Kd) {
    __shared__ unsigned short As[2][128 * 32];  // 8KB each
    __shared__ unsigned short Bs[2][128 * 32];

    int tid = threadIdx.x;
    int lane = tid & 63;
    int w = tid >> 6;
    int wm = w >> 1, wn = w & 1;
    int row0 = blockIdx.y * 128;
    int col0 = blockIdx.x * 128;
    int lr = lane & 15;   // fragment row/col
    int lk = lane >> 4;   // k-group

    f32x4 acc[4][4] = {};

    // stage(buf, k0): each wave issues 2 A-chunks + 2 B-chunks (1KB each)
    auto stage = [&](int buf, int k0) {
#pragma unroll
        for (int s = 0; s < 2; s++) {
            int chunk = w * 2 + s;
            stage_1k(A + (size_t)(row0 + chunk * 16) * Kd + k0, Kd, &As[buf][chunk * 512], lane);
            stage_1k(B + (size_t)(col0 + chunk * 16) * Kd + k0, Kd, &Bs[buf][chunk * 512], lane);
        }
    };

    stage(0, 0);
    __syncthreads();  // vmcnt(0) drain before barrier -> tile 0 visible

    int nk = Kd >> 5;
    for (int kt = 0; kt < nk; kt++) {
        int cur = kt & 1;
        if (kt + 1 < nk) stage(cur ^ 1, (kt + 1) << 5);

        short8 a[4], b[4];
#pragma unroll
        for (int mi = 0; mi < 4; mi++)
            a[mi] = *reinterpret_cast<const short8*>(&As[cur][(wm * 64 + mi * 16 + lr) * 32 + lk * 8]);
#pragma unroll
        for (int ni = 0; ni < 4; ni++)
            b[ni] = *reinterpret_cast<const short8*>(&Bs[cur][(wn * 64 + ni * 16 + lr) * 32 + lk * 8]);
#pragma unroll
        for (int mi = 0; mi < 4; mi++)
#pragma unroll
            for (int ni = 0; ni < 4; ni++)
                acc[mi][ni] = __builtin_amdgcn_mfma_f32_16x16x32_bf16(a[mi], b[ni], acc[mi][ni], 0, 0, 0);

        __syncthreads();  // reads of cur done; next-stage (issued above) drained
    }

    // C/D mapping: col = lane&15, row = (lane>>4)*4 + reg
#pragma unroll
    for (int mi = 0; mi < 4; mi++) {
        int rbase = row0 + wm * 64 + mi * 16 + lk * 4;
#pragma unroll
        for (int ni = 0; ni < 4; ni++) {
            int c = col0 + wn * 64 + ni * 16 + lr;
#pragma unroll
            for (int q = 0; q < 4; q++) {
                int rr = rbase + q;
                float v = acc[mi][ni][q];
                if (MODE == 0) {
                    Cf[(size_t)rr * N + c] = v;
                } else {
                    if (c < INTER_)
                        gateb[(size_t)rr * INTER_ + c] = f2bf(v);
                    else
                        hbcb[(size_t)rr * CONV_DIM_ + (c - INTER_)] = f2bf(v);
                }
            }
        }
    }
}

// ---------------- fp32 dt path ----------------
__global__ void dt_kernel(const float* __restrict__ X, const float* __restrict__ W1,
                          const float* __restrict__ dt_bias, float* __restrict__ dt2) {
    int t = blockIdx.x;
    int tid = threadIdx.x;
    int h = tid >> 2, q = tid & 3;
    const float4* xr = reinterpret_cast<const float4*>(X + (size_t)t * EMB_);
    const float4* wr = reinterpret_cast<const float4*>(W1 + (size_t)(INTER_ + CONV_DIM_ + h) * EMB_);
    int base = q * 128;
    float s0 = 0.f, s1 = 0.f, s2 = 0.f, s3 = 0.f;
#pragma unroll 8
    for (int k4 = 0; k4 < 128; k4++) {
        float4 a = xr[base + k4], b = wr[base + k4];
        s0 = fmaf(a.x, b.x, s0);
        s1 = fmaf(a.y, b.y, s1);
        s2 = fmaf(a.z, b.z, s2);
        s3 = fmaf(a.w, b.w, s3);
    }
    float s = (s0 + s1) + (s2 + s3);
    s += __shfl_xor(s, 1);
    s += __shfl_xor(s, 2);
    if (q == 0) {
        float v = s + dt_bias[h];
        float sp = (v > 20.f) ? v : log1pf(__expf(v));
        dt2[(size_t)t * H_ + h] = sp;
    }
}

// ---------------- depthwise causal conv (K=4) + SiLU, bf16 in/out ----------------
__global__ void conv_kernel(const unsigned short* __restrict__ hbcb, const float* __restrict__ cw,
                            const float* __restrict__ cb, unsigned short* __restrict__ convb) {
    int c = blockIdx.x * 256 + threadIdx.x;  // 0..6143
    int t = blockIdx.y;
    float acc = cb[c];
#pragma unroll
    for (int k = 0; k < K_; k++) {
        int tt = t - (K_ - 1) + k;
        if (tt >= 0)
            acc = fmaf(bf2f(hbcb[(size_t)tt * CONV_DIM_ + c]), cw[c * K_ + k], acc);
    }
    float s = acc * sigmoidf_(acc);
    convb[(size_t)t * CONV_DIM_ + c] = f2bf(s);
}

// ---------------- SSD via MFMA: one block per (chunk, head) ----------------
__launch_bounds__(256, 2)
__global__ void ssd_mfma(const unsigned short* __restrict__ convb, const float* __restrict__ dt2,
                         const float* __restrict__ A_log, const float* __restrict__ Dv,
                         float* __restrict__ ybuf) {
    __shared__ float acum[CS_];                 // log2-scaled cumsum of a = A*dt
    __shared__ unsigned short Bs[64 * 128];     // B j-tile, XOR-swizzled
    __shared__ unsigned short hdT[64 * 64];     // (hid*dt)^T [p][j], swizzled
    __shared__ unsigned short Ps[4][64 * 64];   // per-wave P tile [i][j], swizzled

    int h = blockIdx.x & 63;
    int c = blockIdx.x >> 6;
    int g = h & 7;
    int tid = threadIdx.x;
    int lane = tid & 63;
    int w = tid >> 6;
    int lr = lane & 15, lk = lane >> 4;
    size_t rowbase = (size_t)c * CS_;
    const unsigned short* convB = convb + INTER_ + (size_t)g * N_;
    const unsigned short* convC = convb + INTER_ + G_ * N_ + (size_t)g * N_;
    const unsigned short* convH = convb + (size_t)h * P_;

    float Aneg = -__expf(A_log[h]);
    float mydt = dt2[(rowbase + tid) * H_ + h];
    acum[tid] = Aneg * mydt * LOG2E_;
    __syncthreads();
    for (int off = 1; off < CS_; off <<= 1) {
        float v = (tid >= off) ? acum[tid - off] : 0.f;
        __syncthreads();
        acum[tid] += v;
        __syncthreads();
    }
    float last2 = acum[CS_ - 1];

    int ibase = w * 64;
    float ac_i[4][4];
#pragma unroll
    for (int mi = 0; mi < 4; mi++)
#pragma unroll
        for (int q = 0; q < 4; q++)
            ac_i[mi][q] = acum[ibase + mi * 16 + lk * 4 + q];

    short8 cf[4][4];
#pragma unroll
    for (int mi = 0; mi < 4; mi++) {
        size_t r = rowbase + ibase + mi * 16 + lr;
#pragma unroll
        for (int kt = 0; kt < 4; kt++)
            cf[mi][kt] = *reinterpret_cast<const short8*>(convC + r * CONV_DIM_ + kt * 32 + lk * 8);
    }

    f32x4 accy[4][4] = {};

    for (int jt = 0; jt < 4; jt++) {
        __syncthreads();
#pragma unroll
        for (int u = 0; u < 4; u++) {
            int chunk = u * 256 + tid;
            int j = chunk >> 4, c16 = chunk & 15;
            short8 v = *reinterpret_cast<const short8*>(convB + (rowbase + jt * 64 + j) * CONV_DIM_ + c16 * 8);
            *reinterpret_cast<short8*>(Bs + j * 128 + ((c16 * 8) ^ ((j & 15) << 3))) = v;
        }
#pragma unroll
        for (int u = 0; u < 2; u++) {
            int chunk = u * 256 + tid;
            int j = chunk >> 3, p8 = chunk & 7;
            float dts = dt2[(rowbase + jt * 64 + j) * H_ + h];
            ushort8_t v = *reinterpret_cast<const ushort8_t*>(convH + (rowbase + jt * 64 + j) * CONV_DIM_ + p8 * 8);
#pragma unroll
            for (int e = 0; e < 8; e++) {
                int p = p8 * 8 + e;
                int col = j;
                int swz = (p & 7) << 3;
                hdT[p * 64 + (((col & ~7)) ^ swz) + (col & 7)] = f2bf(bf2f(v[e]) * dts);
            }
        }
        __syncthreads();

        f32x4 acc[4][4] = {};
#pragma unroll
        for (int kt = 0; kt < 4; kt++) {
            short8 bf[4];
#pragma unroll
            for (int ni = 0; ni < 4; ni++) {
                int jb = ni * 16 + lr;
                bf[ni] = *reinterpret_cast<const short8*>(Bs + jb * 128 + ((kt * 32 + lk * 8) ^ ((jb & 15) << 3)));
            }
#pragma unroll
            for (int mi = 0; mi < 4; mi++)
#pragma unroll
                for (int ni = 0; ni < 4; ni++)
                    acc[mi][ni] = __builtin_amdgcn_mfma_f32_16x16x32_bf16(cf[mi][kt], bf[ni], acc[mi][ni], 0, 0, 0);
        }

#pragma unroll
        for (int ni = 0; ni < 4; ni++) {
            int jl = ni * 16 + lr;
            float a_j = acum[jt * 64 + jl];
            int jg = jt * 64 + jl;
#pragma unroll
            for (int mi = 0; mi < 4; mi++) {
#pragma unroll
                for (int q = 0; q < 4; q++) {
                    int il = mi * 16 + lk * 4 + q;
                    int ig = ibase + il;
                    float arg = ac_i[mi][q] - a_j;
                    float e = exp2f(arg + last2);
                    if (jg <= ig) e += exp2f(arg);
                    float pv = acc[mi][ni][q] * e;
                    int swz = (il & 7) << 3;
                    Ps[w][il * 64 + (((jl & ~7)) ^ swz) + (jl & 7)] = f2bf(pv);
                }
            }
        }
        __syncthreads();

#pragma unroll
        for (int jm = 0; jm < 2; jm++) {
            short8 pa[4], hb[4];
#pragma unroll
            for (int mi = 0; mi < 4; mi++) {
                int il = mi * 16 + lr;
                pa[mi] = *reinterpret_cast<const short8*>(Ps[w] + il * 64 + ((jm * 32 + lk * 8) ^ ((il & 7) << 3)));
            }
#pragma unroll
            for (int np = 0; np < 4; np++) {
                int p = np * 16 + lr;
                hb[np] = *reinterpret_cast<const short8*>(hdT + p * 64 + ((jm * 32 + lk * 8) ^ ((p & 7) << 3)));
            }
#pragma unroll
            for (int mi = 0; mi < 4; mi++)
#pragma unroll
                for (int np = 0; np < 4; np++)
                    accy[mi][np] = __builtin_amdgcn_mfma_f32_16x16x32_bf16(pa[mi], hb[np], accy[mi][np], 0, 0, 0);
        }
    }

    float Dh = Dv[h];
#pragma unroll
    for (int mi = 0; mi < 4; mi++) {
#pragma unroll
        for (int q = 0; q < 4; q++) {
            size_t t = rowbase + ibase + mi * 16 + lk * 4 + q;
            const unsigned short* hrow = convH + t * CONV_DIM_;
            float* yrow = ybuf + t * INTER_ + (size_t)h * P_;
#pragma unroll
            for (int np = 0; np < 4; np++) {
                int p = np * 16 + lr;
                yrow[p] = accy[mi][np][q] + Dh * bf2f(hrow[p]);
            }
        }
    }
}

// ---------------- gate-SiLU + RMSNorm -> bf16 ----------------
__global__ void gatenorm_kernel(const float* __restrict__ ybuf, const unsigned short* __restrict__ gateb,
                                const float* __restrict__ norm_w, unsigned short* __restrict__ nb) {
    int t = blockIdx.x;
    int tid = threadIdx.x;
    __shared__ float red[4];
    float yg[16];
    float ss = 0.f;
#pragma unroll
    for (int u = 0; u < 4; u++) {
        int f4 = u * 256 + tid;
        float4 yv = reinterpret_cast<const float4*>(ybuf + (size_t)t * INTER_)[f4];
        ushort4 gu = reinterpret_cast<const ushort4*>(gateb + (size_t)t * INTER_)[f4];
        float g0 = bf2f(gu.x), g1 = bf2f(gu.y), g2 = bf2f(gu.z), g3 = bf2f(gu.w);
        float v0 = yv.x * g0 * sigmoidf_(g0);
        float v1 = yv.y * g1 * sigmoidf_(g1);
        float v2 = yv.z * g2 * sigmoidf_(g2);
        float v3 = yv.w * g3 * sigmoidf_(g3);
        yg[u * 4 + 0] = v0; yg[u * 4 + 1] = v1; yg[u * 4 + 2] = v2; yg[u * 4 + 3] = v3;
        ss += v0 * v0 + v1 * v1 + v2 * v2 + v3 * v3;
    }
#pragma unroll
    for (int off = 32; off > 0; off >>= 1) ss += __shfl_xor(ss, off);
    if ((tid & 63) == 0) red[tid >> 6] = ss;
    __syncthreads();
    float tot = red[0] + red[1] + red[2] + red[3];
    float scale = rsqrtf(tot / (float)INTER_ + 1e-6f);
#pragma unroll
    for (int u = 0; u < 4; u++) {
        int f4 = u * 256 + tid;
        float4 nw = reinterpret_cast<const float4*>(norm_w)[f4];
        ushort4 o;
        o.x = f2bf(nw.x * yg[u * 4 + 0] * scale);
        o.y = f2bf(nw.y * yg[u * 4 + 1] * scale);
        o.z = f2bf(nw.z * yg[u * 4 + 2] * scale);
        o.w = f2bf(nw.w * yg[u * 4 + 3] * scale);
        reinterpret_cast<ushort4*>(nb + (size_t)t * INTER_)[f4] = o;
    }
}

extern "C" void kernel_launch(void* const* d_in, const int* in_sizes, int n_in,
                              void* d_out, int out_size, void* d_ws, size_t ws_size,
                              hipStream_t stream) {
    const float* X    = (const float*)d_in[0];
    const float* W1   = (const float*)d_in[1];
    const float* CW   = (const float*)d_in[2];
    const float* CB   = (const float*)d_in[3];
    const float* DTB  = (const float*)d_in[4];
    const float* ALOG = (const float*)d_in[5];
    const float* DD   = (const float*)d_in[6];
    const float* NW   = (const float*)d_in[7];
    const float* W2   = (const float*)d_in[8];
    float* out = (float*)d_out;

    // ---- workspace layout with lifetime aliasing (total 177,471,488 B) ----
    char* ws = (char*)d_ws;
    unsigned short* W1b   = (unsigned short*)(ws + 0);
    unsigned short* Xb    = (unsigned short*)(ws + 42205184);
    unsigned short* convb = (unsigned short*)(ws + 0);
    unsigned short* nb    = (unsigned short*)(ws + 0);
    unsigned short* gateb = (unsigned short*)(ws + 58982400);
    unsigned short* hbcb  = (unsigned short*)(ws + 92536832);
    float*          ybuf  = (float*)         (ws + 92536832);
    float*          dt2   = (float*)         (ws + 159645696);
    unsigned short* W2b   = (unsigned short*)(ws + 160694272);

    cast_f32_bf16<<<(SEQ_ * EMB_ / 4) / 256, 256, 0, stream>>>(X, Xb, SEQ_ * EMB_ / 4);
    cast_f32_bf16<<<(10304 * EMB_ / 4 + 255) / 256, 256, 0, stream>>>(W1, W1b, 10304 * EMB_ / 4);
    cast_f32_bf16<<<(EMB_ * INTER_ / 4) / 256, 256, 0, stream>>>(W2, W2b, EMB_ * INTER_ / 4);

    dim3 g1(NGEMM1_ / 128, SEQ_ / 128);
    gemm_lds<1><<<g1, 256, 0, stream>>>(Xb, W1b, nullptr, gateb, hbcb, SEQ_, NGEMM1_, EMB_);

    dt_kernel<<<SEQ_, 256, 0, stream>>>(X, W1, DTB, dt2);

    conv_kernel<<<dim3(CONV_DIM_ / 256, SEQ_), 256, 0, stream>>>(hbcb, CW, CB, convb);

    ssd_mfma<<<NC_ * H_, 256, 0, stream>>>(convb, dt2, ALOG, DD, ybuf);

    gatenorm_kernel<<<SEQ_, 256, 0, stream>>>(ybuf, gateb, NW, nb);

    dim3 g2(EMB_ / 128, SEQ_ / 128);
    gemm_lds<0><<<g2, 256, 0, stream>>>(nb, W2b, out, nullptr, nullptr, SEQ_, EMB_, INTER_);
}

// Round 16
// 1032.581 us; speedup vs baseline: 2.7987x; 1.3447x over previous
//
#include <hip/hip_runtime.h>
#include <cstdint>
#include <cstddef>

#define H_ 64
#define P_ 64
#define N_ 128
#define G_ 8
#define K_ 4
#define CS_ 256
#define EMB_ 2048
#define INTER_ 4096
#define CONV_DIM_ 6144
#define NGEMM1_ 10240   // gate + conv columns only (dt handled separately)
#define SEQ_ 4096
#define NC_ 16
#define LOG2E_ 1.44269504f

typedef __attribute__((ext_vector_type(8))) short short8;
typedef __attribute__((ext_vector_type(8))) unsigned short ushort8_t;
typedef __attribute__((ext_vector_type(4))) float f32x4;

__device__ __forceinline__ float bf2f(unsigned short u) {
    return __uint_as_float(((unsigned int)u) << 16);
}
__device__ __forceinline__ unsigned short f2bf(float f) {
    unsigned int x = __float_as_uint(f);
    unsigned int r = (x + 0x7fffu + ((x >> 16) & 1u)) >> 16;  // RNE
    return (unsigned short)r;
}
__device__ __forceinline__ float sigmoidf_(float x) { return 1.f / (1.f + __expf(-x)); }

// ---------------- cast f32 -> bf16 (4 elems/thread) ----------------
__global__ void cast_f32_bf16(const float* __restrict__ in, unsigned short* __restrict__ out, int n4) {
    int i = blockIdx.x * 256 + threadIdx.x;
    if (i < n4) {
        float4 v = reinterpret_cast<const float4*>(in)[i];
        ushort4 o;
        o.x = f2bf(v.x); o.y = f2bf(v.y); o.z = f2bf(v.z); o.w = f2bf(v.w);
        reinterpret_cast<ushort4*>(out)[i] = o;
    }
}

// ---- one 1KB global->LDS staging instruction: 16 rows x 32 bf16 (64B/row) ----
__device__ __forceinline__ void stage_1k(const unsigned short* __restrict__ gsrc, size_t gstride_elems,
                                         unsigned short* lds, int lane) {
    const unsigned short* ga = gsrc + (size_t)(lane >> 2) * gstride_elems + (lane & 3) * 8;
    __builtin_amdgcn_global_load_lds(
        (const __attribute__((address_space(1))) unsigned int*)ga,
        (__attribute__((address_space(3))) unsigned int*)lds,
        16, 0, 0);
}

// ---------------- LDS-staged bf16 MFMA GEMM (m97 pattern): C = A[M,K] . B[N,K]^T ----------------
// 128x128 tile, BK=32, 4 waves (2x2 of 64x64), double-buffered LDS, global_load_lds w=16.
template <int MODE>
__launch_bounds__(256)
__global__ void gemm_lds(const unsigned short* __restrict__ A, const unsigned short* __restrict__ B,
                         float* __restrict__ Cf, unsigned short* __restrict__ gateb,
                         unsigned short* __restrict__ hbcb, int M, int N, int Kd) {
    __shared__ unsigned short As[2][128 * 32];  // 8KB each
    __shared__ unsigned short Bs[2][128 * 32];

    int tid = threadIdx.x;
    int lane = tid & 63;
    int w = tid >> 6;
    int wm = w >> 1, wn = w & 1;
    int row0 = blockIdx.y * 128;
    int col0 = blockIdx.x * 128;
    int lr = lane & 15;   // fragment row/col
    int lk = lane >> 4;   // k-group

    f32x4 acc[4][4] = {};

    // stage(buf, k0): each wave issues 2 A-chunks + 2 B-chunks (1KB each)
    auto stage = [&](int buf, int k0) {
#pragma unroll
        for (int s = 0; s < 2; s++) {
            int chunk = w * 2 + s;
            stage_1k(A + (size_t)(row0 + chunk * 16) * Kd + k0, Kd, &As[buf][chunk * 512], lane);
            stage_1k(B + (size_t)(col0 + chunk * 16) * Kd + k0, Kd, &Bs[buf][chunk * 512], lane);
        }
    };

    stage(0, 0);
    __syncthreads();  // vmcnt(0) drain before barrier -> tile 0 visible

    int nk = Kd >> 5;
    for (int kt = 0; kt < nk; kt++) {
        int cur = kt & 1;
        if (kt + 1 < nk) stage(cur ^ 1, (kt + 1) << 5);

        short8 a[4], b[4];
#pragma unroll
        for (int mi = 0; mi < 4; mi++)
            a[mi] = *reinterpret_cast<const short8*>(&As[cur][(wm * 64 + mi * 16 + lr) * 32 + lk * 8]);
#pragma unroll
        for (int ni = 0; ni < 4; ni++)
            b[ni] = *reinterpret_cast<const short8*>(&Bs[cur][(wn * 64 + ni * 16 + lr) * 32 + lk * 8]);
#pragma unroll
        for (int mi = 0; mi < 4; mi++)
#pragma unroll
            for (int ni = 0; ni < 4; ni++)
                acc[mi][ni] = __builtin_amdgcn_mfma_f32_16x16x32_bf16(a[mi], b[ni], acc[mi][ni], 0, 0, 0);

        __syncthreads();  // reads of cur done; next-stage (issued above) drained
    }

    // C/D mapping: col = lane&15, row = (lane>>4)*4 + reg
#pragma unroll
    for (int mi = 0; mi < 4; mi++) {
        int rbase = row0 + wm * 64 + mi * 16 + lk * 4;
#pragma unroll
        for (int ni = 0; ni < 4; ni++) {
            int c = col0 + wn * 64 + ni * 16 + lr;
#pragma unroll
            for (int q = 0; q < 4; q++) {
                int rr = rbase + q;
                float v = acc[mi][ni][q];
                if (MODE == 0) {
                    Cf[(size_t)rr * N + c] = v;
                } else {
                    if (c < INTER_)
                        gateb[(size_t)rr * INTER_ + c] = f2bf(v);
                    else
                        hbcb[(size_t)rr * CONV_DIM_ + (c - INTER_)] = f2bf(v);
                }
            }
        }
    }
}

// ---------------- fp32 dt path: coalesced, X-in-LDS, 4 t-rows per block ----------------
// Wave w handles h in [w*16, w*16+16); whole wave reads W row contiguously (coalesced),
// FMAs against 4 LDS-resident X rows, shuffle-reduces, lane 0 writes 4 outputs.
__launch_bounds__(256)
__global__ void dt_kernel(const float* __restrict__ X, const float* __restrict__ W1,
                          const float* __restrict__ dt_bias, float* __restrict__ dt2) {
    __shared__ float Xs[4][EMB_];   // 32 KB
    int t0 = blockIdx.x * 4;
    int tid = threadIdx.x;
    int lane = tid & 63;
    int w = tid >> 6;

    // stage 4 X rows: 2048 float4 total, 8 per thread, coalesced
#pragma unroll
    for (int u = 0; u < 8; u++) {
        int idx = u * 256 + tid;          // float4 index 0..2047
        int tt = idx >> 9;                // 512 float4 per row
        int c4 = idx & 511;
        reinterpret_cast<float4*>(Xs[tt])[c4] =
            reinterpret_cast<const float4*>(X + (size_t)(t0 + tt) * EMB_)[c4];
    }
    __syncthreads();

    for (int hh = 0; hh < 16; hh++) {
        int h = w * 16 + hh;
        const float4* wr = reinterpret_cast<const float4*>(W1 + (size_t)(INTER_ + CONV_DIM_ + h) * EMB_);
        float a0 = 0.f, a1 = 0.f, a2 = 0.f, a3 = 0.f;
#pragma unroll
        for (int it = 0; it < 8; it++) {
            float4 wv = wr[it * 64 + lane];
            float4 x0 = reinterpret_cast<const float4*>(Xs[0])[it * 64 + lane];
            float4 x1 = reinterpret_cast<const float4*>(Xs[1])[it * 64 + lane];
            float4 x2 = reinterpret_cast<const float4*>(Xs[2])[it * 64 + lane];
            float4 x3 = reinterpret_cast<const float4*>(Xs[3])[it * 64 + lane];
            a0 = fmaf(wv.x, x0.x, fmaf(wv.y, x0.y, fmaf(wv.z, x0.z, fmaf(wv.w, x0.w, a0))));
            a1 = fmaf(wv.x, x1.x, fmaf(wv.y, x1.y, fmaf(wv.z, x1.z, fmaf(wv.w, x1.w, a1))));
            a2 = fmaf(wv.x, x2.x, fmaf(wv.y, x2.y, fmaf(wv.z, x2.z, fmaf(wv.w, x2.w, a2))));
            a3 = fmaf(wv.x, x3.x, fmaf(wv.y, x3.y, fmaf(wv.z, x3.z, fmaf(wv.w, x3.w, a3))));
        }
#pragma unroll
        for (int off = 32; off > 0; off >>= 1) {
            a0 += __shfl_xor(a0, off);
            a1 += __shfl_xor(a1, off);
            a2 += __shfl_xor(a2, off);
            a3 += __shfl_xor(a3, off);
        }
        if (lane == 0) {
            float bias = dt_bias[h];
            float v0 = a0 + bias, v1 = a1 + bias, v2 = a2 + bias, v3 = a3 + bias;
            dt2[(size_t)(t0 + 0) * H_ + h] = (v0 > 20.f) ? v0 : log1pf(__expf(v0));
            dt2[(size_t)(t0 + 1) * H_ + h] = (v1 > 20.f) ? v1 : log1pf(__expf(v1));
            dt2[(size_t)(t0 + 2) * H_ + h] = (v2 > 20.f) ? v2 : log1pf(__expf(v2));
            dt2[(size_t)(t0 + 3) * H_ + h] = (v3 > 20.f) ? v3 : log1pf(__expf(v3));
        }
    }
}

// ---------------- depthwise causal conv (K=4) + SiLU, bf16 in/out ----------------
__global__ void conv_kernel(const unsigned short* __restrict__ hbcb, const float* __restrict__ cw,
                            const float* __restrict__ cb, unsigned short* __restrict__ convb) {
    int c = blockIdx.x * 256 + threadIdx.x;  // 0..6143
    int t = blockIdx.y;
    float acc = cb[c];
#pragma unroll
    for (int k = 0; k < K_; k++) {
        int tt = t - (K_ - 1) + k;
        if (tt >= 0)
            acc = fmaf(bf2f(hbcb[(size_t)tt * CONV_DIM_ + c]), cw[c * K_ + k], acc);
    }
    float s = acc * sigmoidf_(acc);
    convb[(size_t)t * CONV_DIM_ + c] = f2bf(s);
}

// ---------------- SSD via MFMA: one block per (chunk, head) ----------------
__launch_bounds__(256, 2)
__global__ void ssd_mfma(const unsigned short* __restrict__ convb, const float* __restrict__ dt2,
                         const float* __restrict__ A_log, const float* __restrict__ Dv,
                         float* __restrict__ ybuf) {
    __shared__ float acum[CS_];                 // log2-scaled cumsum of a = A*dt
    __shared__ unsigned short Bs[64 * 128];     // B j-tile, XOR-swizzled
    __shared__ unsigned short hdT[64 * 64];     // (hid*dt)^T [p][j], swizzled
    __shared__ unsigned short Ps[4][64 * 64];   // per-wave P tile [i][j], swizzled

    int h = blockIdx.x & 63;
    int c = blockIdx.x >> 6;
    int g = h & 7;
    int tid = threadIdx.x;
    int lane = tid & 63;
    int w = tid >> 6;
    int lr = lane & 15, lk = lane >> 4;
    size_t rowbase = (size_t)c * CS_;
    const unsigned short* convB = convb + INTER_ + (size_t)g * N_;
    const unsigned short* convC = convb + INTER_ + G_ * N_ + (size_t)g * N_;
    const unsigned short* convH = convb + (size_t)h * P_;

    float Aneg = -__expf(A_log[h]);
    float mydt = dt2[(rowbase + tid) * H_ + h];
    acum[tid] = Aneg * mydt * LOG2E_;
    __syncthreads();
    for (int off = 1; off < CS_; off <<= 1) {
        float v = (tid >= off) ? acum[tid - off] : 0.f;
        __syncthreads();
        acum[tid] += v;
        __syncthreads();
    }
    float last2 = acum[CS_ - 1];

    int ibase = w * 64;
    float ac_i[4][4];
#pragma unroll
    for (int mi = 0; mi < 4; mi++)
#pragma unroll
        for (int q = 0; q < 4; q++)
            ac_i[mi][q] = acum[ibase + mi * 16 + lk * 4 + q];

    short8 cf[4][4];
#pragma unroll
    for (int mi = 0; mi < 4; mi++) {
        size_t r = rowbase + ibase + mi * 16 + lr;
#pragma unroll
        for (int kt = 0; kt < 4; kt++)
            cf[mi][kt] = *reinterpret_cast<const short8*>(convC + r * CONV_DIM_ + kt * 32 + lk * 8);
    }

    f32x4 accy[4][4] = {};

    for (int jt = 0; jt < 4; jt++) {
        __syncthreads();
#pragma unroll
        for (int u = 0; u < 4; u++) {
            int chunk = u * 256 + tid;
            int j = chunk >> 4, c16 = chunk & 15;
            short8 v = *reinterpret_cast<const short8*>(convB + (rowbase + jt * 64 + j) * CONV_DIM_ + c16 * 8);
            *reinterpret_cast<short8*>(Bs + j * 128 + ((c16 * 8) ^ ((j & 15) << 3))) = v;
        }
#pragma unroll
        for (int u = 0; u < 2; u++) {
            int chunk = u * 256 + tid;
            int j = chunk >> 3, p8 = chunk & 7;
            float dts = dt2[(rowbase + jt * 64 + j) * H_ + h];
            ushort8_t v = *reinterpret_cast<const ushort8_t*>(convH + (rowbase + jt * 64 + j) * CONV_DIM_ + p8 * 8);
#pragma unroll
            for (int e = 0; e < 8; e++) {
                int p = p8 * 8 + e;
                int col = j;
                int swz = (p & 7) << 3;
                hdT[p * 64 + (((col & ~7)) ^ swz) + (col & 7)] = f2bf(bf2f(v[e]) * dts);
            }
        }
        __syncthreads();

        f32x4 acc[4][4] = {};
#pragma unroll
        for (int kt = 0; kt < 4; kt++) {
            short8 bf[4];
#pragma unroll
            for (int ni = 0; ni < 4; ni++) {
                int jb = ni * 16 + lr;
                bf[ni] = *reinterpret_cast<const short8*>(Bs + jb * 128 + ((kt * 32 + lk * 8) ^ ((jb & 15) << 3)));
            }
#pragma unroll
            for (int mi = 0; mi < 4; mi++)
#pragma unroll
                for (int ni = 0; ni < 4; ni++)
                    acc[mi][ni] = __builtin_amdgcn_mfma_f32_16x16x32_bf16(cf[mi][kt], bf[ni], acc[mi][ni], 0, 0, 0);
        }

#pragma unroll
        for (int ni = 0; ni < 4; ni++) {
            int jl = ni * 16 + lr;
            float a_j = acum[jt * 64 + jl];
            int jg = jt * 64 + jl;
#pragma unroll
            for (int mi = 0; mi < 4; mi++) {
#pragma unroll
                for (int q = 0; q < 4; q++) {
                    int il = mi * 16 + lk * 4 + q;
                    int ig = ibase + il;
                    float arg = ac_i[mi][q] - a_j;
                    float e = exp2f(arg + last2);
                    if (jg <= ig) e += exp2f(arg);
                    float pv = acc[mi][ni][q] * e;
                    int swz = (il & 7) << 3;
                    Ps[w][il * 64 + (((jl & ~7)) ^ swz) + (jl & 7)] = f2bf(pv);
                }
            }
        }
        __syncthreads();

#pragma unroll
        for (int jm = 0; jm < 2; jm++) {
            short8 pa[4], hb[4];
#pragma unroll
            for (int mi = 0; mi < 4; mi++) {
                int il = mi * 16 + lr;
                pa[mi] = *reinterpret_cast<const short8*>(Ps[w] + il * 64 + ((jm * 32 + lk * 8) ^ ((il & 7) << 3)));
            }
#pragma unroll
            for (int np = 0; np < 4; np++) {
                int p = np * 16 + lr;
                hb[np] = *reinterpret_cast<const short8*>(hdT + p * 64 + ((jm * 32 + lk * 8) ^ ((p & 7) << 3)));
            }
#pragma unroll
            for (int mi = 0; mi < 4; mi++)
#pragma unroll
                for (int np = 0; np < 4; np++)
                    accy[mi][np] = __builtin_amdgcn_mfma_f32_16x16x32_bf16(pa[mi], hb[np], accy[mi][np], 0, 0, 0);
        }
    }

    float Dh = Dv[h];
#pragma unroll
    for (int mi = 0; mi < 4; mi++) {
#pragma unroll
        for (int q = 0; q < 4; q++) {
            size_t t = rowbase + ibase + mi * 16 + lk * 4 + q;
            const unsigned short* hrow = convH + t * CONV_DIM_;
            float* yrow = ybuf + t * INTER_ + (size_t)h * P_;
#pragma unroll
            for (int np = 0; np < 4; np++) {
                int p = np * 16 + lr;
                yrow[p] = accy[mi][np][q] + Dh * bf2f(hrow[p]);
            }
        }
    }
}

// ---------------- gate-SiLU + RMSNorm -> bf16 ----------------
__global__ void gatenorm_kernel(const float* __restrict__ ybuf, const unsigned short* __restrict__ gateb,
                                const float* __restrict__ norm_w, unsigned short* __restrict__ nb) {
    int t = blockIdx.x;
    int tid = threadIdx.x;
    __shared__ float red[4];
    float yg[16];
    float ss = 0.f;
#pragma unroll
    for (int u = 0; u < 4; u++) {
        int f4 = u * 256 + tid;
        float4 yv = reinterpret_cast<const float4*>(ybuf + (size_t)t * INTER_)[f4];
        ushort4 gu = reinterpret_cast<const ushort4*>(gateb + (size_t)t * INTER_)[f4];
        float g0 = bf2f(gu.x), g1 = bf2f(gu.y), g2 = bf2f(gu.z), g3 = bf2f(gu.w);
        float v0 = yv.x * g0 * sigmoidf_(g0);
        float v1 = yv.y * g1 * sigmoidf_(g1);
        float v2 = yv.z * g2 * sigmoidf_(g2);
        float v3 = yv.w * g3 * sigmoidf_(g3);
        yg[u * 4 + 0] = v0; yg[u * 4 + 1] = v1; yg[u * 4 + 2] = v2; yg[u * 4 + 3] = v3;
        ss += v0 * v0 + v1 * v1 + v2 * v2 + v3 * v3;
    }
#pragma unroll
    for (int off = 32; off > 0; off >>= 1) ss += __shfl_xor(ss, off);
    if ((tid & 63) == 0) red[tid >> 6] = ss;
    __syncthreads();
    float tot = red[0] + red[1] + red[2] + red[3];
    float scale = rsqrtf(tot / (float)INTER_ + 1e-6f);
#pragma unroll
    for (int u = 0; u < 4; u++) {
        int f4 = u * 256 + tid;
        float4 nw = reinterpret_cast<const float4*>(norm_w)[f4];
        ushort4 o;
        o.x = f2bf(nw.x * yg[u * 4 + 0] * scale);
        o.y = f2bf(nw.y * yg[u * 4 + 1] * scale);
        o.z = f2bf(nw.z * yg[u * 4 + 2] * scale);
        o.w = f2bf(nw.w * yg[u * 4 + 3] * scale);
        reinterpret_cast<ushort4*>(nb + (size_t)t * INTER_)[f4] = o;
    }
}

extern "C" void kernel_launch(void* const* d_in, const int* in_sizes, int n_in,
                              void* d_out, int out_size, void* d_ws, size_t ws_size,
                              hipStream_t stream) {
    const float* X    = (const float*)d_in[0];
    const float* W1   = (const float*)d_in[1];
    const float* CW   = (const float*)d_in[2];
    const float* CB   = (const float*)d_in[3];
    const float* DTB  = (const float*)d_in[4];
    const float* ALOG = (const float*)d_in[5];
    const float* DD   = (const float*)d_in[6];
    const float* NW   = (const float*)d_in[7];
    const float* W2   = (const float*)d_in[8];
    float* out = (float*)d_out;

    // ---- workspace layout with lifetime aliasing (total 177,471,488 B) ----
    char* ws = (char*)d_ws;
    unsigned short* W1b   = (unsigned short*)(ws + 0);
    unsigned short* Xb    = (unsigned short*)(ws + 42205184);
    unsigned short* convb = (unsigned short*)(ws + 0);
    unsigned short* nb    = (unsigned short*)(ws + 0);
    unsigned short* gateb = (unsigned short*)(ws + 58982400);
    unsigned short* hbcb  = (unsigned short*)(ws + 92536832);
    float*          ybuf  = (float*)         (ws + 92536832);
    float*          dt2   = (float*)         (ws + 159645696);
    unsigned short* W2b   = (unsigned short*)(ws + 160694272);

    cast_f32_bf16<<<(SEQ_ * EMB_ / 4) / 256, 256, 0, stream>>>(X, Xb, SEQ_ * EMB_ / 4);
    cast_f32_bf16<<<(10304 * EMB_ / 4 + 255) / 256, 256, 0, stream>>>(W1, W1b, 10304 * EMB_ / 4);
    cast_f32_bf16<<<(EMB_ * INTER_ / 4) / 256, 256, 0, stream>>>(W2, W2b, EMB_ * INTER_ / 4);

    dim3 g1(NGEMM1_ / 128, SEQ_ / 128);
    gemm_lds<1><<<g1, 256, 0, stream>>>(Xb, W1b, nullptr, gateb, hbcb, SEQ_, NGEMM1_, EMB_);

    dt_kernel<<<SEQ_ / 4, 256, 0, stream>>>(X, W1, DTB, dt2);

    conv_kernel<<<dim3(CONV_DIM_ / 256, SEQ_), 256, 0, stream>>>(hbcb, CW, CB, convb);

    ssd_mfma<<<NC_ * H_, 256, 0, stream>>>(convb, dt2, ALOG, DD, ybuf);

    gatenorm_kernel<<<SEQ_, 256, 0, stream>>>(ybuf, gateb, NW, nb);

    dim3 g2(EMB_ / 128, SEQ_ / 128);
    gemm_lds<0><<<g2, 256, 0, stream>>>(nb, W2b, out, nullptr, nullptr, SEQ_, EMB_, INTER_);
}